// Round 14
// baseline (377.905 us; speedup 1.0000x reference)
//
#include <hip/hip_runtime.h>
#include <hip/hip_cooperative_groups.h>
#include <hip/hip_bf16.h>
#include <hip/hip_fp16.h>

namespace cg = cooperative_groups;

#define IN_DIM 128
#define OUT_DIM 64
#define MAXDEG 64   // padded-CSR stride; deg ~ Poisson(16), P(>=64) ~ 1e-24 (guarded)

typedef __attribute__((ext_vector_type(8))) short short8v;   // 8 bf16 (4 VGPRs)
typedef __attribute__((ext_vector_type(4))) float float4v;   // MFMA acc
typedef unsigned short ushort_t;
typedef unsigned int uint_t;

__device__ inline ushort_t f_to_bf16(float f) {
    uint_t x = __float_as_uint(f);
    uint_t r = (x + 0x7fffu + ((x >> 16) & 1u)) >> 16;   // RNE
    return (ushort_t)r;
}

// ---------------------------------------------------------------------------
// Phase bodies as __device__ functions — shared byte-for-byte between the
// single cooperative kernel (primary) and the 3-kernel fallback path.
// ---------------------------------------------------------------------------

// Proj (R12-proven): one wave = 16 nodes x 64 dims, K=128, 16x16x32 bf16
// MFMA, W pre-swizzled in LDS, hoisted h loads, a-partial epilogue.
__device__ __forceinline__ void proj_phase(
    int pb,
    const float* __restrict__ h, const float* __restrict__ W,
    const float* __restrict__ Wb, const float* __restrict__ Aw,
    ushort_t* __restrict__ Whb, float* __restrict__ a_dst_arr,
    float* __restrict__ a_src_arr, int N)
{
    __shared__ ushort_t Wl[16 * 64 * 8];   // 16 KB
    const int t = threadIdx.x;

    {   // stage W -> LDS: coalesced float4 reads, swizzled LDS writes
        const int k     = t >> 1;
        const int dbase = (t & 1) * 32;
        const int kb    = k >> 5;
        const int quad  = (k >> 3) & 3;
        const int j     = k & 7;
        #pragma unroll
        for (int i = 0; i < 8; i++) {
            float4 w4 = *(const float4*)(W + k * OUT_DIM + dbase + i * 4);
            float wv[4] = {w4.x, w4.y, w4.z, w4.w};
            #pragma unroll
            for (int c = 0; c < 4; c++) {
                int d = dbase + i * 4 + c;
                int f = ((kb * 4 + (d >> 4)) * 64 + quad * 16 + (d & 15)) * 8 + j;
                Wl[f] = f_to_bf16(wv[c]);
            }
        }
    }
    __syncthreads();

    const int wave  = t >> 6;
    const int lane  = t & 63;
    const int node0 = (pb * 4 + wave) * 16;
    if (node0 >= N) return;
    const int quad = lane >> 4;
    const int col  = lane & 15;

    const int rowc = min(node0 + col, N - 1);   // clamp for ragged tail
    const float* __restrict__ arow = h + (size_t)rowc * IN_DIM;

    float4 hr[4][2];
    #pragma unroll
    for (int kb = 0; kb < 4; kb++) {
        const float* ap = arow + kb * 32 + quad * 8;
        hr[kb][0] = *(const float4*)ap;
        hr[kb][1] = *(const float4*)(ap + 4);
    }

    float4v acc[4];
    #pragma unroll
    for (int db = 0; db < 4; db++) acc[db] = (float4v){0.f, 0.f, 0.f, 0.f};

    #pragma unroll
    for (int kb = 0; kb < 4; kb++) {
        union { short8v v; ushort_t u[8]; } af;
        af.u[0] = f_to_bf16(hr[kb][0].x); af.u[1] = f_to_bf16(hr[kb][0].y);
        af.u[2] = f_to_bf16(hr[kb][0].z); af.u[3] = f_to_bf16(hr[kb][0].w);
        af.u[4] = f_to_bf16(hr[kb][1].x); af.u[5] = f_to_bf16(hr[kb][1].y);
        af.u[6] = f_to_bf16(hr[kb][1].z); af.u[7] = f_to_bf16(hr[kb][1].w);
        #pragma unroll
        for (int db = 0; db < 4; db++) {
            short8v bf = *(const short8v*)&Wl[(((kb << 2) | db) * 64 + lane) * 8];
            acc[db] = __builtin_amdgcn_mfma_f32_16x16x32_bf16(af.v, bf, acc[db], 0, 0, 0);
        }
    }

    float wbv[4], awd[4], aws[4];
    #pragma unroll
    for (int db = 0; db < 4; db++) {
        wbv[db] = Wb[db * 16 + col];
        awd[db] = Aw[db * 16 + col];
        aws[db] = Aw[OUT_DIM + db * 16 + col];
    }

    float pd[4] = {0.f, 0.f, 0.f, 0.f};
    float ps[4] = {0.f, 0.f, 0.f, 0.f};
    #pragma unroll
    for (int db = 0; db < 4; db++) {
        #pragma unroll
        for (int r = 0; r < 4; r++) {
            float v = acc[db][r] + wbv[db];
            int node = node0 + quad * 4 + r;
            if (node < N)
                Whb[(size_t)node * OUT_DIM + db * 16 + col] = f_to_bf16(v);
            pd[r] = fmaf(v, awd[db], pd[r]);
            ps[r] = fmaf(v, aws[db], ps[r]);
        }
    }
    #pragma unroll
    for (int r = 0; r < 4; r++) {
        float d_ = pd[r], s_ = ps[r];
        #pragma unroll
        for (int off = 1; off < 16; off <<= 1) {
            d_ += __shfl_xor(d_, off);
            s_ += __shfl_xor(s_, off);
        }
        int node = node0 + quad * 4 + r;
        if (col == 0 && node < N) {
            a_dst_arr[node] = d_;
            a_src_arr[node] = s_;
        }
    }
}

// Scatter (R9-proven shape: 4 edges/thread; more occupancy measured WORSE).
// Record = (fp16(a_src[s]) | src16); a_dst gather deleted (R9 win 54->44.6).
// ~45us is the RMW-transaction-pipe floor (R13: byte traffic is not the
// binding term — partitioning halved WRITE, duration unchanged).
__device__ __forceinline__ void scatter_phase(
    int tid, int nthr,
    const int* __restrict__ src, const int* __restrict__ dst,
    const float* __restrict__ a_src_arr,
    int* __restrict__ cnt, uint_t* __restrict__ csr, int E)
{
    for (int base = tid * 4; base + 4 <= E; base += nthr * 4) {
        int4 s4 = *(const int4*)&src[base];
        int4 t4 = *(const int4*)&dst[base];
        int ss[4] = {s4.x, s4.y, s4.z, s4.w};
        int tt[4] = {t4.x, t4.y, t4.z, t4.w};
        #pragma unroll
        for (int i = 0; i < 4; i++) {
            float as = a_src_arr[ss[i]];
            uint_t rec = (((uint_t)__half_as_ushort(__float2half(as))) << 16)
                       | (uint_t)(ss[i] & 0xffff);
            int r = atomicAdd(&cnt[tt[i]], 1);
            if (r < MAXDEG) csr[tt[i] * MAXDEG + r] = rec;
        }
    }
    if (tid == 0) {                       // tail (E%4), empty for E=800000
        for (int e = E & ~3; e < E; e++) {
            int s = src[e], d = dst[e];
            float as = a_src_arr[s];
            uint_t rec = (((uint_t)__half_as_ushort(__float2half(as))) << 16)
                       | (uint_t)(s & 0xffff);
            int r = atomicAdd(&cnt[d], 1);
            if (r < MAXDEG) csr[d * MAXDEG + r] = rec;
        }
    }
}

// Agg (R9-proven): two-phase per node; Phase A computes w from wave-uniform
// a_dst + record's fp16 a_src; Phase B: 8 lanes/edge, uint4/lane, 16 rows
// in flight; butterfly combine; 2x float4 out.
__device__ __forceinline__ void agg_phase(
    int gw, int nwaves,
    const int* __restrict__ cnt, const uint_t* __restrict__ csr,
    const uint_t* __restrict__ Whb2,
    const float* __restrict__ a_dst_arr, float ab,
    float* __restrict__ out, int N)
{
    const int lane = threadIdx.x & 63;
    const int el = lane >> 3;
    const int dl = lane & 7;

    for (int nu = gw; nu < N; nu += nwaves) {
        int u   = __builtin_amdgcn_readfirstlane(nu);
        int deg = min(cnt[u], MAXDEG);
        const uint_t* __restrict__ seg = csr + (size_t)u * MAXDEG;

        float ad = a_dst_arr[u] + ab;
        int   s_l = 0;
        float w_l = 0.f;
        if (lane < deg) {
            uint_t rec = seg[lane];
            s_l = (int)(rec & 0xffffu);
            float as = __half2float(__ushort_as_half((ushort_t)(rec >> 16)));
            float v  = ad + as;
            v = (v > 0.0f) ? v : 0.2f * v;
            w_l = __expf(v);
        }
        float ws = w_l;
        #pragma unroll
        for (int off = 1; off < 64; off <<= 1) ws += __shfl_xor(ws, off);
        float inv  = (deg > 0) ? 1.0f / ws : 0.0f;
        float al_l = w_l * inv;

        float acc[8];
        #pragma unroll
        for (int i = 0; i < 8; i++) acc[i] = 0.f;

        for (int j = 0; j < deg; j += 16) {
            int   e0  = j + el;
            int   e1  = j + 8 + el;
            int   ss0 = __shfl(s_l, e0);
            float al0 = __shfl(al_l, e0);
            int   ss1 = __shfl(s_l, e1);
            float al1 = __shfl(al_l, e1);
            al0 = (e0 < deg) ? al0 : 0.0f;
            al1 = (e1 < deg) ? al1 : 0.0f;
            uint4 p0 = *(const uint4*)&Whb2[(size_t)ss0 * 32 + dl * 4];
            uint4 p1 = *(const uint4*)&Whb2[(size_t)ss1 * 32 + dl * 4];
            acc[0] = fmaf(al0, __uint_as_float(p0.x << 16),        acc[0]);
            acc[1] = fmaf(al0, __uint_as_float(p0.x & 0xffff0000u), acc[1]);
            acc[2] = fmaf(al0, __uint_as_float(p0.y << 16),        acc[2]);
            acc[3] = fmaf(al0, __uint_as_float(p0.y & 0xffff0000u), acc[3]);
            acc[4] = fmaf(al0, __uint_as_float(p0.z << 16),        acc[4]);
            acc[5] = fmaf(al0, __uint_as_float(p0.z & 0xffff0000u), acc[5]);
            acc[6] = fmaf(al0, __uint_as_float(p0.w << 16),        acc[6]);
            acc[7] = fmaf(al0, __uint_as_float(p0.w & 0xffff0000u), acc[7]);
            acc[0] = fmaf(al1, __uint_as_float(p1.x << 16),        acc[0]);
            acc[1] = fmaf(al1, __uint_as_float(p1.x & 0xffff0000u), acc[1]);
            acc[2] = fmaf(al1, __uint_as_float(p1.y << 16),        acc[2]);
            acc[3] = fmaf(al1, __uint_as_float(p1.y & 0xffff0000u), acc[3]);
            acc[4] = fmaf(al1, __uint_as_float(p1.z << 16),        acc[4]);
            acc[5] = fmaf(al1, __uint_as_float(p1.z & 0xffff0000u), acc[5]);
            acc[6] = fmaf(al1, __uint_as_float(p1.w << 16),        acc[6]);
            acc[7] = fmaf(al1, __uint_as_float(p1.w & 0xffff0000u), acc[7]);
        }

        #pragma unroll
        for (int off = 8; off < 64; off <<= 1) {
            #pragma unroll
            for (int i = 0; i < 8; i++) acc[i] += __shfl_xor(acc[i], off);
        }

        if (lane < 8) {
            float4 o0 = make_float4(acc[0], acc[1], acc[2], acc[3]);
            float4 o1 = make_float4(acc[4], acc[5], acc[6], acc[7]);
            *(float4*)&out[(size_t)u * OUT_DIM + dl * 8]     = o0;
            *(float4*)&out[(size_t)u * OUT_DIM + dl * 8 + 4] = o1;
        }
    }
}

// ---------------------------------------------------------------------------
// PRIMARY: single cooperative kernel — proj -> grid.sync -> scatter ->
// grid.sync -> agg. Deletes 2 of 3 kernel launches (>= 21us of measured
// inter-dispatch overhead: R9 kernel-sum <= 134us vs total 155.5us).
// Grid = 784 blocks (reproduces R9's exact scatter shape);
// __launch_bounds__(256,4) caps VGPR at 128 -> >= 4 blocks/CU co-resident
// capacity (1024 >= 784), so cooperative validation passes.
// ---------------------------------------------------------------------------
__global__ __launch_bounds__(256, 4) void gat_all(
    const float* __restrict__ h, const float* __restrict__ W,
    const float* __restrict__ Wb, const float* __restrict__ Aw,
    const float* __restrict__ Ab,
    ushort_t* __restrict__ Whb, float* __restrict__ a_dst_arr,
    float* __restrict__ a_src_arr, int* __restrict__ cnt,
    uint_t* __restrict__ csr,
    const int* __restrict__ src, const int* __restrict__ dst,
    float* __restrict__ out, int N, int E, int PB)
{
    cg::grid_group grid = cg::this_grid();
    const int bid = (int)blockIdx.x;
    const int nb  = (int)gridDim.x;
    const int tid = bid * 256 + (int)threadIdx.x;

    // phase 1: cnt zero + projection
    for (int i = tid; i < N; i += nb * 256) cnt[i] = 0;
    for (int pb = bid; pb < PB; pb += nb)
        proj_phase(pb, h, W, Wb, Aw, Whb, a_dst_arr, a_src_arr, N);

    grid.sync();

    // phase 2: scatter (R9 shape: with 784 blocks, one 4-edge chunk/thread)
    scatter_phase(tid, nb * 256, src, dst, a_src_arr, cnt, csr, E);

    grid.sync();

    // phase 3: gather-aggregate (wave-strided over nodes)
    int gw = bid * 4 + ((int)threadIdx.x >> 6);
    agg_phase(gw, nb * 4, cnt, csr, (const uint_t*)Whb, a_dst_arr, Ab[0],
              out, N);
}

// ---------------------------------------------------------------------------
// FALLBACK: the R13-proven 3-kernel pipeline (used only if the cooperative
// launch is rejected). Same phase bodies.
// ---------------------------------------------------------------------------
__global__ __launch_bounds__(256) void gat_proj(
    const float* __restrict__ h, const float* __restrict__ W,
    const float* __restrict__ Wb, const float* __restrict__ Aw,
    ushort_t* __restrict__ Whb, float* __restrict__ a_dst_arr,
    float* __restrict__ a_src_arr, int* __restrict__ cnt, int N)
{
    for (int i = (int)blockIdx.x * 256 + (int)threadIdx.x; i < N;
         i += (int)gridDim.x * 256)
        cnt[i] = 0;
    proj_phase((int)blockIdx.x, h, W, Wb, Aw, Whb, a_dst_arr, a_src_arr, N);
}

__global__ __launch_bounds__(256) void gat_scatter(
    const int* __restrict__ src, const int* __restrict__ dst,
    const float* __restrict__ a_src_arr,
    int* __restrict__ cnt, uint_t* __restrict__ csr, int E)
{
    scatter_phase((int)(blockIdx.x * blockDim.x + threadIdx.x),
                  (int)(gridDim.x * blockDim.x), src, dst, a_src_arr,
                  cnt, csr, E);
}

__global__ __launch_bounds__(256) void gat_agg(
    const int* __restrict__ cnt, const uint_t* __restrict__ csr,
    const uint_t* __restrict__ Whb2,
    const float* __restrict__ a_dst_arr, const float* __restrict__ Ab,
    float* __restrict__ out, int N)
{
    int gw = (int)blockIdx.x * 4 + ((int)threadIdx.x >> 6);
    agg_phase(gw, (int)gridDim.x * 4, cnt, csr, Whb2, a_dst_arr, Ab[0],
              out, N);
}

extern "C" void kernel_launch(void* const* d_in, const int* in_sizes, int n_in,
                              void* d_out, int out_size, void* d_ws, size_t ws_size,
                              hipStream_t stream)
{
    const float* h   = (const float*)d_in[0];
    const float* W_w = (const float*)d_in[1];
    const float* W_b = (const float*)d_in[2];
    const float* A_w = (const float*)d_in[3];
    const float* A_b = (const float*)d_in[4];
    const int*   src = (const int*)d_in[5];
    const int*   dst = (const int*)d_in[6];
    float* out = (float*)d_out;

    int N = in_sizes[0] / IN_DIM;   // 50000
    int E = in_sizes[5];            // 800000

    // Workspace: Whb[N*64 u16] | a_dst[N] | a_src[N] | cnt[N] | csr[N*MAXDEG u32]
    ushort_t* Whb   = (ushort_t*)d_ws;
    float* a_dst_a  = (float*)(Whb + (size_t)N * OUT_DIM);
    float* a_src_a  = a_dst_a + N;
    int*   cnt      = (int*)(a_src_a + N);
    uint_t* csr     = (uint_t*)(cnt + N);

    int waves = (N + 15) / 16;
    int PB = (waves + 3) / 4;                       // 782

    // PRIMARY: one cooperative kernel (784 blocks = R9 scatter shape)
    void* args[] = {&h, &W_w, &W_b, &A_w, &A_b, &Whb, &a_dst_a, &a_src_a,
                    &cnt, &csr, &src, &dst, &out, &N, &E, &PB};
    hipError_t err = hipLaunchCooperativeKernel(
        reinterpret_cast<void*>(gat_all), dim3(784), dim3(256), args, 0, stream);

    if (err != hipSuccess) {
        // FALLBACK: R13-proven 3-kernel pipeline
        gat_proj<<<PB, 256, 0, stream>>>(h, W_w, W_b, A_w, Whb,
                                         a_dst_a, a_src_a, cnt, N);
        int grid = (E / 4 + 255) / 256;
        gat_scatter<<<grid, 256, 0, stream>>>(src, dst, a_src_a, cnt, csr, E);
        int agrid = (N + 3) / 4;
        gat_agg<<<agrid, 256, 0, stream>>>(cnt, csr, (const uint_t*)Whb,
                                           a_dst_a, A_b, out, N);
    }
}

// Round 15
// 154.649 us; speedup vs baseline: 2.4436x; 2.4436x over previous
//
#include <hip/hip_runtime.h>
#include <hip/hip_bf16.h>
#include <hip/hip_fp16.h>

#define IN_DIM 128
#define OUT_DIM 64
#define MAXDEG 64   // padded-CSR stride; deg ~ Poisson(16), P(>=64) ~ 1e-24 (guarded)
#define NPART 8     // dst-range partitions ~ XCDs

typedef __attribute__((ext_vector_type(8))) short short8v;   // 8 bf16 (4 VGPRs)
typedef __attribute__((ext_vector_type(4))) float float4v;   // MFMA acc
typedef unsigned short ushort_t;
typedef unsigned int uint_t;

__device__ inline ushort_t f_to_bf16(float f) {
    uint_t x = __float_as_uint(f);
    uint_t r = (x + 0x7fffu + ((x >> 16) & 1u)) >> 16;   // RNE
    return (ushort_t)r;
}

// ---------------------------------------------------------------------------
// K1: MFMA projection + a-partial epilogue (R12/R13-proven).
// Hoisted h loads (8 float4s in flight), coalesced W->LDS staging, cnt zero
// prologue. MFMA layouts (m89-verified): A[m=lane&15][k=quad*8+j],
// B[k=quad*8+j][n=lane&15], C/D col=lane&15, row=quad*4+reg.
// ---------------------------------------------------------------------------
__global__ __launch_bounds__(256) void gat_proj(
    const float* __restrict__ h, const float* __restrict__ W,
    const float* __restrict__ Wb, const float* __restrict__ Aw,
    ushort_t* __restrict__ Whb, float* __restrict__ a_dst_arr,
    float* __restrict__ a_src_arr, int* __restrict__ cnt, int N)
{
    __shared__ ushort_t Wl[16 * 64 * 8];   // 16 KB

    const int t = threadIdx.x;

    for (int i = (int)blockIdx.x * 256 + t; i < N; i += (int)gridDim.x * 256)
        cnt[i] = 0;

    {   // stage W -> LDS: coalesced float4 reads, swizzled LDS writes
        const int k     = t >> 1;
        const int dbase = (t & 1) * 32;
        const int kb    = k >> 5;
        const int quad  = (k >> 3) & 3;
        const int j     = k & 7;
        #pragma unroll
        for (int i = 0; i < 8; i++) {
            float4 w4 = *(const float4*)(W + k * OUT_DIM + dbase + i * 4);
            float wv[4] = {w4.x, w4.y, w4.z, w4.w};
            #pragma unroll
            for (int c = 0; c < 4; c++) {
                int d = dbase + i * 4 + c;
                int f = ((kb * 4 + (d >> 4)) * 64 + quad * 16 + (d & 15)) * 8 + j;
                Wl[f] = f_to_bf16(wv[c]);
            }
        }
    }
    __syncthreads();

    const int wave  = t >> 6;
    const int lane  = t & 63;
    const int node0 = ((int)blockIdx.x * 4 + wave) * 16;
    if (node0 >= N) return;
    const int quad = lane >> 4;
    const int col  = lane & 15;

    const int rowc = min(node0 + col, N - 1);   // clamp for ragged tail
    const float* __restrict__ arow = h + (size_t)rowc * IN_DIM;

    float4 hr[4][2];
    #pragma unroll
    for (int kb = 0; kb < 4; kb++) {
        const float* ap = arow + kb * 32 + quad * 8;
        hr[kb][0] = *(const float4*)ap;
        hr[kb][1] = *(const float4*)(ap + 4);
    }

    float4v acc[4];
    #pragma unroll
    for (int db = 0; db < 4; db++) acc[db] = (float4v){0.f, 0.f, 0.f, 0.f};

    #pragma unroll
    for (int kb = 0; kb < 4; kb++) {
        union { short8v v; ushort_t u[8]; } af;
        af.u[0] = f_to_bf16(hr[kb][0].x); af.u[1] = f_to_bf16(hr[kb][0].y);
        af.u[2] = f_to_bf16(hr[kb][0].z); af.u[3] = f_to_bf16(hr[kb][0].w);
        af.u[4] = f_to_bf16(hr[kb][1].x); af.u[5] = f_to_bf16(hr[kb][1].y);
        af.u[6] = f_to_bf16(hr[kb][1].z); af.u[7] = f_to_bf16(hr[kb][1].w);
        #pragma unroll
        for (int db = 0; db < 4; db++) {
            short8v bf = *(const short8v*)&Wl[(((kb << 2) | db) * 64 + lane) * 8];
            acc[db] = __builtin_amdgcn_mfma_f32_16x16x32_bf16(af.v, bf, acc[db], 0, 0, 0);
        }
    }

    float wbv[4], awd[4], aws[4];
    #pragma unroll
    for (int db = 0; db < 4; db++) {
        wbv[db] = Wb[db * 16 + col];
        awd[db] = Aw[db * 16 + col];
        aws[db] = Aw[OUT_DIM + db * 16 + col];
    }

    float pd[4] = {0.f, 0.f, 0.f, 0.f};
    float ps[4] = {0.f, 0.f, 0.f, 0.f};
    #pragma unroll
    for (int db = 0; db < 4; db++) {
        #pragma unroll
        for (int r = 0; r < 4; r++) {
            float v = acc[db][r] + wbv[db];
            int node = node0 + quad * 4 + r;
            if (node < N)
                Whb[(size_t)node * OUT_DIM + db * 16 + col] = f_to_bf16(v);
            pd[r] = fmaf(v, awd[db], pd[r]);
            ps[r] = fmaf(v, aws[db], ps[r]);
        }
    }
    #pragma unroll
    for (int r = 0; r < 4; r++) {
        float d_ = pd[r], s_ = ps[r];
        #pragma unroll
        for (int off = 1; off < 16; off <<= 1) {
            d_ += __shfl_xor(d_, off);
            s_ += __shfl_xor(s_, off);
        }
        int node = node0 + quad * 4 + r;
        if (col == 0 && node < N) {
            a_dst_arr[node] = d_;
            a_src_arr[node] = s_;
        }
    }
}

// ---------------------------------------------------------------------------
// K2: scatter, DST-RANGE PARTITIONED (R13-measured: WRITE 48->31.8MB via
// L2 write-combining; duration ~flat -> kernel is RMW-transaction-bound at
// ~45us, its floor in this algorithm family). Partition p = blockIdx&7 owns
// dst range [p*span,(p+1)*span); its csr slice (1.6MB) + cnt slice are
// L2-resident. Each partition streams all src/dst (L3-absorbed).
// Record = (fp16(a_src[s]) | src16); a_dst gather deleted (R9 win).
// ---------------------------------------------------------------------------
__global__ __launch_bounds__(256) void gat_scatter(
    const int* __restrict__ src, const int* __restrict__ dst,
    const float* __restrict__ a_src_arr,
    int* __restrict__ cnt, uint_t* __restrict__ csr, int E,
    int span, int BPP)
{
    const int p  = (int)blockIdx.x & (NPART - 1);   // partition (~XCD)
    const int q  = (int)blockIdx.x >> 3;            // block within partition
    const int lo = p * span;
    const int hi = lo + span;
    const int stride = BPP * 256 * 4;

    for (int base = (q * 256 + (int)threadIdx.x) * 4; base + 4 <= E;
         base += stride) {
        int4 s4 = *(const int4*)&src[base];
        int4 t4 = *(const int4*)&dst[base];
        int ss[4] = {s4.x, s4.y, s4.z, s4.w};
        int tt[4] = {t4.x, t4.y, t4.z, t4.w};
        #pragma unroll
        for (int i = 0; i < 4; i++) {
            if (tt[i] >= lo && tt[i] < hi) {
                float as = a_src_arr[ss[i]];
                uint_t rec = (((uint_t)__half_as_ushort(__float2half(as))) << 16)
                           | (uint_t)(ss[i] & 0xffff);
                int r = atomicAdd(&cnt[tt[i]], 1);
                if (r < MAXDEG) csr[tt[i] * MAXDEG + r] = rec;
            }
        }
    }
    // tail (E%4 != 0): handled by partition 0, block 0
    if (p == 0 && q == 0 && threadIdx.x == 0) {
        for (int e = E & ~3; e < E; e++) {
            int s = src[e], d = dst[e];
            float as = a_src_arr[s];
            uint_t rec = (((uint_t)__half_as_ushort(__float2half(as))) << 16)
                       | (uint_t)(s & 0xffff);
            int r = atomicAdd(&cnt[d], 1);
            if (r < MAXDEG) csr[d * MAXDEG + r] = rec;
        }
    }
}

// ---------------------------------------------------------------------------
// K3: gather-aggregate, two-phase (R9-proven). One wave per node — full
// TLP (12500 blocks; R14 proved capping this to a cooperative grid is a
// >2.5x loss). Phase A: ad = a_dst[u] + Ab (wave-uniform); lane e<deg
// reads record e, w = exp(leaky(ad + fp16 a_src)). Butterfly wsum,
// pre-normalized alpha. Phase B: 8 lanes/edge, uint4 per lane, 16 rows in
// flight; masked slots row 0, alpha 0. Butterfly-combine, 2x float4 out.
// ---------------------------------------------------------------------------
__global__ __launch_bounds__(256) void gat_agg(
    const int* __restrict__ cnt, const uint_t* __restrict__ csr,
    const uint_t* __restrict__ Whb2,
    const float* __restrict__ a_dst_arr, const float* __restrict__ Ab,
    float* __restrict__ out, int N)
{
    int node = (int)((blockIdx.x * blockDim.x + threadIdx.x) >> 6);
    int lane = threadIdx.x & 63;
    if (node >= N) return;
    int u   = __builtin_amdgcn_readfirstlane(node);
    int deg = min(cnt[u], MAXDEG);
    const uint_t* __restrict__ seg = csr + (size_t)u * MAXDEG;

    // ---- Phase A ----
    float ad = a_dst_arr[u] + Ab[0];      // wave-uniform
    int   s_l = 0;
    float w_l = 0.f;
    if (lane < deg) {
        uint_t rec = seg[lane];
        s_l = (int)(rec & 0xffffu);
        float as = __half2float(__ushort_as_half((ushort_t)(rec >> 16)));
        float v  = ad + as;
        v = (v > 0.0f) ? v : 0.2f * v;
        w_l = __expf(v);
    }
    float ws = w_l;
    #pragma unroll
    for (int off = 1; off < 64; off <<= 1) ws += __shfl_xor(ws, off);
    float inv  = (deg > 0) ? 1.0f / ws : 0.0f;
    float al_l = w_l * inv;               // pre-normalized alpha in lane e

    // ---- Phase B ----
    const int el = lane >> 3;   // edge slot within group (0..7)
    const int dl = lane & 7;    // dim octet: dims [8*dl, 8*dl+8)

    float acc[8];
    #pragma unroll
    for (int i = 0; i < 8; i++) acc[i] = 0.f;

    for (int j = 0; j < deg; j += 16) {
        int   e0  = j + el;
        int   e1  = j + 8 + el;
        int   ss0 = __shfl(s_l, e0);
        float al0 = __shfl(al_l, e0);
        int   ss1 = __shfl(s_l, e1);
        float al1 = __shfl(al_l, e1);
        al0 = (e0 < deg) ? al0 : 0.0f;    // masked slots: row 0, alpha 0
        al1 = (e1 < deg) ? al1 : 0.0f;
        uint4 p0 = *(const uint4*)&Whb2[(size_t)ss0 * 32 + dl * 4];
        uint4 p1 = *(const uint4*)&Whb2[(size_t)ss1 * 32 + dl * 4];
        acc[0] = fmaf(al0, __uint_as_float(p0.x << 16),        acc[0]);
        acc[1] = fmaf(al0, __uint_as_float(p0.x & 0xffff0000u), acc[1]);
        acc[2] = fmaf(al0, __uint_as_float(p0.y << 16),        acc[2]);
        acc[3] = fmaf(al0, __uint_as_float(p0.y & 0xffff0000u), acc[3]);
        acc[4] = fmaf(al0, __uint_as_float(p0.z << 16),        acc[4]);
        acc[5] = fmaf(al0, __uint_as_float(p0.z & 0xffff0000u), acc[5]);
        acc[6] = fmaf(al0, __uint_as_float(p0.w << 16),        acc[6]);
        acc[7] = fmaf(al0, __uint_as_float(p0.w & 0xffff0000u), acc[7]);
        acc[0] = fmaf(al1, __uint_as_float(p1.x << 16),        acc[0]);
        acc[1] = fmaf(al1, __uint_as_float(p1.x & 0xffff0000u), acc[1]);
        acc[2] = fmaf(al1, __uint_as_float(p1.y << 16),        acc[2]);
        acc[3] = fmaf(al1, __uint_as_float(p1.y & 0xffff0000u), acc[3]);
        acc[4] = fmaf(al1, __uint_as_float(p1.z << 16),        acc[4]);
        acc[5] = fmaf(al1, __uint_as_float(p1.z & 0xffff0000u), acc[5]);
        acc[6] = fmaf(al1, __uint_as_float(p1.w << 16),        acc[6]);
        acc[7] = fmaf(al1, __uint_as_float(p1.w & 0xffff0000u), acc[7]);
    }

    // Combine the 8 edge-slot groups (lanes {dl, dl+8, ..., dl+56}).
    #pragma unroll
    for (int off = 8; off < 64; off <<= 1) {
        #pragma unroll
        for (int i = 0; i < 8; i++) acc[i] += __shfl_xor(acc[i], off);
    }

    if (lane < 8) {
        float4 o0 = make_float4(acc[0], acc[1], acc[2], acc[3]);
        float4 o1 = make_float4(acc[4], acc[5], acc[6], acc[7]);
        *(float4*)&out[(size_t)u * OUT_DIM + dl * 8]     = o0;
        *(float4*)&out[(size_t)u * OUT_DIM + dl * 8 + 4] = o1;
    }
}

extern "C" void kernel_launch(void* const* d_in, const int* in_sizes, int n_in,
                              void* d_out, int out_size, void* d_ws, size_t ws_size,
                              hipStream_t stream)
{
    const float* h   = (const float*)d_in[0];
    const float* W_w = (const float*)d_in[1];
    const float* W_b = (const float*)d_in[2];
    const float* A_w = (const float*)d_in[3];
    const float* A_b = (const float*)d_in[4];
    const int*   src = (const int*)d_in[5];
    const int*   dst = (const int*)d_in[6];
    float* out = (float*)d_out;

    const int N = in_sizes[0] / IN_DIM;   // 50000
    const int E = in_sizes[5];            // 800000

    // Workspace: Whb[N*64 u16] | a_dst[N] | a_src[N] | cnt[N] | csr[N*MAXDEG u32]
    ushort_t* Whb   = (ushort_t*)d_ws;
    float* a_dst_a  = (float*)(Whb + (size_t)N * OUT_DIM);
    float* a_src_a  = a_dst_a + N;
    int*   cnt      = (int*)(a_src_a + N);
    uint_t* csr     = (uint_t*)(cnt + N);

    {   // K1: MFMA projection (+ cnt zeroing; no memset dispatch)
        int waves = (N + 15) / 16;
        int PB = (waves + 3) / 4;                   // 4 waves/block -> 782
        gat_proj<<<PB, 256, 0, stream>>>(h, W_w, W_b, A_w, Whb,
                                         a_dst_a, a_src_a, cnt, N);
    }
    {   // K2: dst-partitioned scatter (8 partitions x BPP blocks)
        int BPP  = 98;                              // blocks per partition
        int span = (N + NPART - 1) / NPART;         // 6250
        gat_scatter<<<BPP * NPART, 256, 0, stream>>>(src, dst, a_src_a,
                                                     cnt, csr, E, span, BPP);
    }
    {   // K3: two-phase gather-aggregate (full-TLP grid)
        int grid = (N + 3) / 4;
        gat_agg<<<grid, 256, 0, stream>>>(cnt, csr, (const uint_t*)Whb,
                                          a_dst_a, A_b, out, N);
    }
}